// Round 1
// baseline (662.438 us; speedup 1.0000x reference)
//
#include <hip/hip_runtime.h>

#define NS     32768
#define NA     2048
#define ASZ    1024
#define NB     4
#define SIGP   34816
#define BM     128
#define BN     128
#define BKK    64
#define TILES  4096      /* (NA/BM)*(NS/BN) = 16*256 */
#define CAP    8192
#define MARGIN 2.0f
#define NEGINF -3.0e38f

typedef unsigned short u16;
typedef __attribute__((ext_vector_type(8))) short bf16x8;
typedef __attribute__((ext_vector_type(4))) float f32x4;

__device__ __forceinline__ u16 f2bf(float f) {
  union { float f; unsigned u; } x; x.f = f;
  unsigned r = x.u + 0x7FFF + ((x.u >> 16) & 1);   // RNE
  return (u16)(r >> 16);
}

// ---------------- prep: atoms -> bf16 ----------------
__global__ void prep_atoms_k(const float* __restrict__ atoms, u16* __restrict__ abf) {
  int a = blockIdx.x;
  const float* srow = atoms + (size_t)a * ASZ;
  u16* drow = abf + (size_t)a * ASZ;
  for (int k = threadIdx.x; k < ASZ; k += 256) drow[k] = f2bf(srow[k]);
}

// ---------------- prep: 8 shifted zero-padded signal copies (bf16) + fp32 copy ----------------
// sig_logical[i] = orig[i-512] (zero outside). copy m holds sig_logical[i+m].
__global__ void prep_sig_k(const float* __restrict__ orig, u16* __restrict__ sigsh,
                           float* __restrict__ sigf) {
  int i = blockIdx.x * 256 + threadIdx.x;
  if (i >= SIGP) return;
  int b = blockIdx.y >> 3, m = blockIdx.y & 7;
  int j = i + m - 512;
  float f = (j >= 0 && j < NS) ? orig[(size_t)b * NS + j] : 0.0f;
  sigsh[(size_t)(b * 8 + m) * SIGP + i] = f2bf(f);
  if (m == 0) sigf[(size_t)b * SIGP + i] = f;
}

// ---------------- main correlation GEMM (bf16 MFMA, 128x128 tile, BK=64) ----------------
// EMIT=0: write per-tile max. EMIT=1: recompute gated tiles, emit candidates >= thr-MARGIN.
template<int EMIT>
__global__ __launch_bounds__(256, 2)
void corr_gemm(const u16* __restrict__ abf, const u16* __restrict__ sigsh,
               float* __restrict__ tmax, const float* __restrict__ thr,
               int* __restrict__ ccnt, float* __restrict__ cval, int* __restrict__ cidx)
{
  // XCD-aware swizzle (nwg = 16384, divisible by 8 -> bijective)
  int bid0 = blockIdx.x;
  int bid  = (bid0 & 7) * ((NB * TILES) >> 3) + (bid0 >> 3);

  int b = bid >> 12;            // 4096 tiles per batch
  int tile = bid & 4095;
  float cut = 0.0f;
  if (EMIT) {
    cut = thr[b] - MARGIN;
    if (tmax[b * TILES + tile] < cut) return;   // uniform per block
  }
  int mt = tile >> 8, nt = tile & 255;
  int m0 = mt * BM, t0 = nt * BN;

  __shared__ u16 Al[BM * BKK];      // A tile [128][64], XOR-swizzled 16B slots
  __shared__ u16 Bl[BN * BKK];      // B^T tile [128 t][64 k], XOR-swizzled
  __shared__ float wred[4];

  int tid = threadIdx.x;
  int w = tid >> 6, lane = tid & 63;
  int wr = w >> 1, wc = w & 1;

  const u16* Ab = abf + (size_t)m0 * ASZ;
  const u16* Sb = sigsh + (size_t)b * 8 * SIGP;

  // staging lane constants: chunk = 8 rows x 64 elems (1 KB). lane covers row lr, stored slot ls.
  int lr = lane >> 3;               // 0..7 (also the shift-copy index for B rows)
  int ls = lane & 7;
  int cs = ls ^ lr;                 // logical 16B slot fetched into stored slot ls (row&7 == lr)

  f32x4 acc[4][4];
  #pragma unroll
  for (int i = 0; i < 4; i++)
    #pragma unroll
    for (int j = 0; j < 4; j++)
      acc[i][j] = (f32x4){0.f, 0.f, 0.f, 0.f};

  int arow = wr * 64 + (lane & 15);
  int brow = wc * 64 + (lane & 15);
  int kgrp = lane >> 4;

  for (int k0 = 0; k0 < ASZ; k0 += BKK) {
    #pragma unroll
    for (int i = 0; i < 8; i++) {
      int c = w * 8 + i;            // 32 chunks: 0..15 A, 16..31 B^T
      if (c < 16) {
        const u16* src = Ab + (size_t)(c * 8 + lr) * ASZ + k0 + cs * 8;
        __builtin_amdgcn_global_load_lds((const __attribute__((address_space(1))) void*)src,
            (__attribute__((address_space(3))) void*)(&Al[c * 512]), 16, 0, 0);
      } else {
        int c2 = c - 16;
        // B^T row r = c2*8+lr (time), source = shifted copy lr at aligned offset
        const u16* src = Sb + (size_t)lr * SIGP + t0 + c2 * 8 + k0 + cs * 8;
        __builtin_amdgcn_global_load_lds((const __attribute__((address_space(1))) void*)src,
            (__attribute__((address_space(3))) void*)(&Bl[c2 * 512]), 16, 0, 0);
      }
    }
    __syncthreads();
    #pragma unroll
    for (int ks = 0; ks < 2; ks++) {
      int slot = ks * 4 + kgrp;     // logical 8-elem K slot 0..7
      bf16x8 af[4], bfr[4];
      #pragma unroll
      for (int mf = 0; mf < 4; mf++) {
        int row = arow + mf * 16;
        af[mf] = *(const bf16x8*)&Al[row * 64 + ((slot ^ (row & 7)) * 8)];
      }
      #pragma unroll
      for (int nf = 0; nf < 4; nf++) {
        int row = brow + nf * 16;
        bfr[nf] = *(const bf16x8*)&Bl[row * 64 + ((slot ^ (row & 7)) * 8)];
      }
      #pragma unroll
      for (int mf = 0; mf < 4; mf++)
        #pragma unroll
        for (int nf = 0; nf < 4; nf++)
          acc[mf][nf] = __builtin_amdgcn_mfma_f32_16x16x32_bf16(af[mf], bfr[nf], acc[mf][nf], 0, 0, 0);
    }
    __syncthreads();
  }

  if (!EMIT) {
    float lmax = NEGINF;
    #pragma unroll
    for (int mf = 0; mf < 4; mf++)
      #pragma unroll
      for (int nf = 0; nf < 4; nf++)
        #pragma unroll
        for (int q = 0; q < 4; q++)
          lmax = fmaxf(lmax, acc[mf][nf][q]);
    #pragma unroll
    for (int off2 = 32; off2; off2 >>= 1) lmax = fmaxf(lmax, __shfl_xor(lmax, off2, 64));
    if (lane == 0) wred[w] = lmax;
    __syncthreads();
    if (tid == 0)
      tmax[b * TILES + tile] = fmaxf(fmaxf(wred[0], wred[1]), fmaxf(wred[2], wred[3]));
  } else {
    #pragma unroll
    for (int mf = 0; mf < 4; mf++)
      #pragma unroll
      for (int nf = 0; nf < 4; nf++)
        #pragma unroll
        for (int q = 0; q < 4; q++) {
          float v = acc[mf][nf][q];
          if (v >= cut) {
            int a = m0 + wr * 64 + mf * 16 + 4 * kgrp + q;   // C/D: row=(lane>>4)*4+reg
            int t = t0 + wc * 64 + nf * 16 + (lane & 15);    // C/D: col=lane&15
            int pos = atomicAdd(&ccnt[b], 1);
            if (pos < CAP) {
              cval[b * CAP + pos] = v;
              cidx[b * CAP + pos] = (a << 15) | t;
            }
          }
        }
  }
}

// ---------------- threshold: 64th largest tile-max per batch ----------------
__global__ void thresh_k(const float* __restrict__ tmax, float* __restrict__ thr,
                         int* __restrict__ ccnt) {
  int b = blockIdx.x, tid = threadIdx.x;
  __shared__ float v[TILES];
  __shared__ float bv[256];
  __shared__ int bi[256];
  __shared__ float cur;
  for (int i = tid; i < TILES; i += 256) v[i] = tmax[b * TILES + i];
  __syncthreads();
  for (int r = 0; r < 64; r++) {
    float best = NEGINF; int bidx = -1;
    for (int i = tid; i < TILES; i += 256)
      if (v[i] > best) { best = v[i]; bidx = i; }
    bv[tid] = best; bi[tid] = bidx;
    __syncthreads();
    for (int s = 128; s; s >>= 1) {
      if (tid < s && bv[tid + s] > bv[tid]) { bv[tid] = bv[tid + s]; bi[tid] = bi[tid + s]; }
      __syncthreads();
    }
    if (tid == 0) { cur = bv[0]; v[bi[0]] = NEGINF; }
    __syncthreads();
  }
  if (tid == 0) { thr[b] = cur; ccnt[b] = 0; }
}

// ---------------- rescore candidates exactly in fp32 (one wave each) ----------------
__global__ void rescore_k(const float* __restrict__ atoms, const float* __restrict__ sigf,
                          const int* __restrict__ ccnt, const int* __restrict__ cidx,
                          float* __restrict__ cval) {
  int gw = blockIdx.x * 4 + (threadIdx.x >> 6);
  int lane = threadIdx.x & 63;
  int b = gw >> 13, ci = gw & 8191;
  if (b >= NB) return;
  int cnt = ccnt[b]; if (cnt > CAP) cnt = CAP;
  if (ci >= cnt) return;
  int idx = cidx[b * CAP + ci];
  int a = idx >> 15, t = idx & (NS - 1);
  const float* ap = atoms + (size_t)a * ASZ;
  const float* sp = sigf + (size_t)b * SIGP + t;
  float sum = 0.f;
  #pragma unroll
  for (int j = 0; j < 16; j++) { int k = lane + 64 * j; sum += ap[k] * sp[k]; }
  #pragma unroll
  for (int off = 32; off; off >>= 1) sum += __shfl_xor(sum, off, 64);
  if (lane == 0) cval[b * CAP + ci] = sum;
}

// ---------------- select top-64 per batch (value desc, tie: index asc) ----------------
__global__ void select_k(const int* __restrict__ ccnt, float* __restrict__ cval,
                         const int* __restrict__ cidx, float* __restrict__ sval,
                         int* __restrict__ sidx) {
  int b = blockIdx.x, tid = threadIdx.x;
  int cnt = ccnt[b]; if (cnt > CAP) cnt = CAP;
  __shared__ float bv[256];
  __shared__ int bix[256];
  __shared__ int bslot[256];
  for (int r = 0; r < 64; r++) {
    float best = NEGINF; int bestidx = 0x7FFFFFFF; int bs = -1;
    for (int i = tid; i < cnt; i += 256) {
      float v = cval[b * CAP + i]; int id = cidx[b * CAP + i];
      if (v > best || (v == best && id < bestidx)) { best = v; bestidx = id; bs = i; }
    }
    bv[tid] = best; bix[tid] = bestidx; bslot[tid] = bs;
    __syncthreads();
    for (int s = 128; s; s >>= 1) {
      if (tid < s) {
        bool take = (bv[tid + s] > bv[tid]) ||
                    (bv[tid + s] == bv[tid] && bix[tid + s] < bix[tid]);
        if (take) { bv[tid] = bv[tid + s]; bix[tid] = bix[tid + s]; bslot[tid] = bslot[tid + s]; }
      }
      __syncthreads();
    }
    if (tid == 0) {
      sval[b * 64 + r] = bv[0];
      sidx[b * 64 + r] = bix[0];
      if (bslot[0] >= 0) cval[b * CAP + bslot[0]] = NEGINF;   // knockout
    }
    __syncthreads();
  }
}

// ---------------- deterministic reconstruction (one thread per output sample) ----------------
__global__ void recon_k(const float* __restrict__ atoms, const float* __restrict__ sval,
                        const int* __restrict__ sidx, float* __restrict__ out) {
  int gp = blockIdx.x * 256 + threadIdx.x;       // 0 .. NB*NS-1
  int b = gp >> 15, p = gp & (NS - 1);
  __shared__ float vv[64];
  __shared__ int ii[64];
  if (threadIdx.x < 64) {
    vv[threadIdx.x] = sval[b * 64 + threadIdx.x];
    ii[threadIdx.x] = sidx[b * 64 + threadIdx.x];
  }
  __syncthreads();
  float acc = 0.f;
  for (int s = 0; s < 64; s++) {
    int idx = ii[s];
    int a = idx >> 15, t = idx & (NS - 1);
    int off = p - t;
    if (off >= 0 && off < ASZ) acc += vv[s] * atoms[(size_t)a * ASZ + off];
  }
  out[gp] = acc;
}

extern "C" void kernel_launch(void* const* d_in, const int* in_sizes, int n_in,
                              void* d_out, int out_size, void* d_ws, size_t ws_size,
                              hipStream_t stream) {
  const float* orig  = (const float*)d_in[0];   // (4,1,32768) fp32
  const float* atoms = (const float*)d_in[1];   // (2048,1024) fp32
  float* out = (float*)d_out;                   // (4,1,32768) fp32
  char* ws = (char*)d_ws;

  // workspace layout (all 256B-aligned, total ~7.3 MB)
  u16*   abf   = (u16*)  (ws + 0);          // 4,194,304 : atoms bf16
  u16*   sigsh = (u16*)  (ws + 4194304);    // 2,228,224 : 8 shifted padded signal copies, bf16
  float* sigf  = (float*)(ws + 6422528);    //   557,056 : padded signal fp32
  float* tmax  = (float*)(ws + 6979584);    //    65,536 : per-tile maxima
  float* thr   = (float*)(ws + 7045120);    //       256 : per-batch threshold
  int*   ccnt  = (int*)  (ws + 7045376);    //       256 : candidate counts
  float* cval  = (float*)(ws + 7045632);    //   131,072 : candidate values
  int*   cidx  = (int*)  (ws + 7176704);    //   131,072 : candidate flat indices
  float* sval  = (float*)(ws + 7307776);    //     1,024 : selected values
  int*   sidx  = (int*)  (ws + 7308800);    //     1,024 : selected indices

  prep_atoms_k<<<NA, 256, 0, stream>>>(atoms, abf);
  prep_sig_k<<<dim3(SIGP / 256, NB * 8), 256, 0, stream>>>(orig, sigsh, sigf);
  corr_gemm<0><<<NB * TILES, 256, 0, stream>>>(abf, sigsh, tmax, thr, ccnt, cval, cidx);
  thresh_k<<<NB, 256, 0, stream>>>(tmax, thr, ccnt);
  corr_gemm<1><<<NB * TILES, 256, 0, stream>>>(abf, sigsh, tmax, thr, ccnt, cval, cidx);
  rescore_k<<<8192, 256, 0, stream>>>(atoms, sigf, ccnt, cidx, cval);
  select_k<<<NB, 256, 0, stream>>>(ccnt, cval, cidx, sval, sidx);
  recon_k<<<out_size / 256, 256, 0, stream>>>(atoms, sval, sidx, out);
}

// Round 2
// 357.572 us; speedup vs baseline: 1.8526x; 1.8526x over previous
//
#include <hip/hip_runtime.h>

#define NS     32768
#define NA     2048
#define ASZ    1024
#define NB     4
#define SIGC   34848          /* padded shifted-copy length, mult of 16 */
#define BM     128
#define BN     128
#define BK     128
#define TILES  4096           /* (NA/BM)*(NS/BN) */
#define CAP    8192
#define MINT   5080           /* margin 2.0 in int units (2.0*127*20) */
#define SSCALE 20.0f

typedef signed char s8;
typedef __attribute__((ext_vector_type(4))) int i32x4;
typedef __attribute__((ext_vector_type(16))) int i32x16;

__device__ __forceinline__ int imax(int a, int b) { return a > b ? a : b; }

// ---------------- prep: atoms -> i8 (x127), also zero worklist counter ----------------
__global__ void prep_atoms_k(const float* __restrict__ atoms, s8* __restrict__ abf,
                             int* __restrict__ wlc) {
  if (blockIdx.x == 0 && threadIdx.x == 0) *wlc = 0;
  int a = blockIdx.x;
  const float* srow = atoms + (size_t)a * ASZ;
  s8* drow = abf + (size_t)a * ASZ;
  for (int k = threadIdx.x; k < ASZ; k += 256) {
    float q = fminf(127.f, fmaxf(-127.f, srow[k] * 127.f));
    drow[k] = (s8)__float2int_rn(q);
  }
}

// ---------------- prep: 16 shifted zero-padded i8 signal copies + fp32 copy ----------------
// sig_logical[i] = orig[i-512] (zero outside). copy m holds sig_logical[i+m], m=0..15.
__global__ void prep_sig_k(const float* __restrict__ orig, s8* __restrict__ sigsh,
                           float* __restrict__ sigf) {
  int i = blockIdx.x * 256 + threadIdx.x;
  if (i >= SIGC) return;
  int b = blockIdx.y >> 4, m = blockIdx.y & 15;
  int j = i + m - 512;
  float f = (j >= 0 && j < NS) ? orig[(size_t)b * NS + j] : 0.0f;
  float q = fminf(127.f, fmaxf(-127.f, f * SSCALE));
  sigsh[(size_t)(b * 16 + m) * SIGC + i] = (s8)__float2int_rn(q);
  if (m == 0) sigf[(size_t)b * SIGC + i] = f;
}

// ---------------- pass 1: i8 screening GEMM, per-tile max (exact int32) ----------------
__global__ __launch_bounds__(256, 4)
void screen1(const s8* __restrict__ abf, const s8* __restrict__ sigsh,
             int* __restrict__ tmax)
{
  __shared__ __align__(16) s8 Al[BM * BK];   // 16 KB  [row][128B], 16B slots XOR-swizzled
  __shared__ __align__(16) s8 Bl[BN * BK];   // 16 KB
  int bid0 = blockIdx.x;
  int bid  = (bid0 & 7) * ((NB * TILES) >> 3) + (bid0 >> 3);   // XCD swizzle (16384 % 8 == 0)
  int b = bid >> 12, tile = bid & 4095;
  int mt = tile >> 8, nt = tile & 255;
  int m0 = mt * BM, t0 = nt * BN;
  int tid = threadIdx.x, w = tid >> 6, lane = tid & 63;
  int wr = w >> 1, wc = w & 1;
  int lr = lane >> 3, ls = lane & 7, cs = ls ^ lr;   // stage: row lr of chunk, stored slot ls
  const s8* Ab = abf + (size_t)m0 * ASZ;
  const s8* Sb = sigsh + (size_t)b * 16 * SIGC;

  i32x16 acc[2][2];
  #pragma unroll
  for (int i = 0; i < 2; i++)
    #pragma unroll
    for (int j = 0; j < 2; j++)
      #pragma unroll
      for (int q = 0; q < 16; q++) acc[i][j][q] = 0;

  int arow = wr * 64 + (lane & 31);
  int brow = wc * 64 + (lane & 31);
  int kg = lane >> 5;

  for (int k0 = 0; k0 < ASZ; k0 += BK) {
    #pragma unroll
    for (int i = 0; i < 8; i++) {
      int c = w * 8 + i;                 // 32 chunks: 0..15 A, 16..31 B^T; 8 rows x 128B each
      if (c < 16) {
        const s8* src = Ab + (size_t)(c * 8 + lr) * ASZ + k0 + cs * 16;
        __builtin_amdgcn_global_load_lds((const __attribute__((address_space(1))) void*)src,
            (__attribute__((address_space(3))) void*)(&Al[c * 1024]), 16, 0, 0);
      } else {
        int c2 = c - 16;
        int m = 8 * (c2 & 1) + lr;       // shift-copy index = (c2*8+lr) & 15
        const s8* src = Sb + (size_t)m * SIGC + t0 + 16 * (c2 >> 1) + k0 + cs * 16;
        __builtin_amdgcn_global_load_lds((const __attribute__((address_space(1))) void*)src,
            (__attribute__((address_space(3))) void*)(&Bl[c2 * 1024]), 16, 0, 0);
      }
    }
    __syncthreads();
    #pragma unroll
    for (int kk = 0; kk < 4; kk++) {
      i32x4 af[2], bfr[2];
      #pragma unroll
      for (int mf = 0; mf < 2; mf++) {
        int row = arow + mf * 32;
        int slot = (kk * 2 + kg) ^ (row & 7);
        af[mf] = *(const i32x4*)&Al[row * BK + slot * 16];
      }
      #pragma unroll
      for (int nf = 0; nf < 2; nf++) {
        int row = brow + nf * 32;
        int slot = (kk * 2 + kg) ^ (row & 7);
        bfr[nf] = *(const i32x4*)&Bl[row * BK + slot * 16];
      }
      #pragma unroll
      for (int mf = 0; mf < 2; mf++)
        #pragma unroll
        for (int nf = 0; nf < 2; nf++)
          acc[mf][nf] = __builtin_amdgcn_mfma_i32_32x32x32_i8(af[mf], bfr[nf], acc[mf][nf], 0, 0, 0);
    }
    __syncthreads();
  }

  int lmax = -2147483647;
  #pragma unroll
  for (int mf = 0; mf < 2; mf++)
    #pragma unroll
    for (int nf = 0; nf < 2; nf++)
      #pragma unroll
      for (int q = 0; q < 16; q++) lmax = imax(lmax, acc[mf][nf][q]);
  #pragma unroll
  for (int off = 32; off; off >>= 1) lmax = imax(lmax, __shfl_xor(lmax, off, 64));
  int* wredp = (int*)Al;
  if (lane == 0) wredp[w] = lmax;
  __syncthreads();
  if (tid == 0)
    tmax[b * TILES + tile] = imax(imax(wredp[0], wredp[1]), imax(wredp[2], wredp[3]));
}

// ---------------- threshold: 64th-largest tile-max (2-level histogram) + worklist ----------------
__global__ void thresh_k(const int* __restrict__ tmax, int* __restrict__ thr,
                         int* __restrict__ ccnt, int* __restrict__ wl, int* __restrict__ wlc) {
  int b = blockIdx.x, tid = threadIdx.x;
  __shared__ int hist[4096];
  __shared__ int tsum[256];
  __shared__ int hist2[256];
  __shared__ int sB1, sAbove, sThr;
  for (int i = tid; i < 4096; i += 256) hist[i] = 0;
  __syncthreads();
  for (int i = tid; i < TILES; i += 256) {
    unsigned u = (unsigned)tmax[b * TILES + i] ^ 0x80000000u;
    atomicAdd(&hist[u >> 20], 1);
  }
  __syncthreads();
  { int s = 0;
    for (int j = 0; j < 16; j++) s += hist[tid * 16 + j];
    tsum[tid] = s; }
  __syncthreads();
  if (tid == 0) {
    int cum = 0, T = 0;
    for (int t2 = 255; t2 >= 0; t2--) {
      if (cum + tsum[t2] >= 64) { T = t2; break; }
      cum += tsum[t2];
    }
    int B1 = T * 16;
    for (int bk = T * 16 + 15; bk >= T * 16; bk--) {
      if (cum + hist[bk] >= 64) { B1 = bk; break; }
      cum += hist[bk];
    }
    sB1 = B1; sAbove = cum;
  }
  __syncthreads();
  if (tid < 256) hist2[tid] = 0;
  __syncthreads();
  int B1 = sB1;
  for (int i = tid; i < TILES; i += 256) {
    unsigned u = (unsigned)tmax[b * TILES + i] ^ 0x80000000u;
    if ((int)(u >> 20) == B1) atomicAdd(&hist2[(u >> 12) & 255], 1);
  }
  __syncthreads();
  if (tid == 0) {
    int cum = sAbove, B2 = 0;
    for (int z = 255; z >= 0; z--) { cum += hist2[z]; if (cum >= 64) { B2 = z; break; } }
    unsigned ulow = ((unsigned)B1 << 20) | ((unsigned)B2 << 12);
    int t = (int)(ulow ^ 0x80000000u);
    sThr = t; thr[b] = t; ccnt[b] = 0;
  }
  __syncthreads();
  int cut = sThr - MINT;
  for (int i = tid; i < TILES; i += 256)
    if (tmax[b * TILES + i] >= cut) { int p = atomicAdd(wlc, 1); wl[p] = (b << 12) | i; }
}

// ---------------- pass 2: recompute gated tiles from worklist, emit candidate indices ----------------
__global__ __launch_bounds__(256, 4)
void screen2(const s8* __restrict__ abf, const s8* __restrict__ sigsh,
             const int* __restrict__ thr, const int* __restrict__ wl,
             const int* __restrict__ wlc, int* __restrict__ ccnt, int* __restrict__ cidx)
{
  __shared__ __align__(16) s8 Al[BM * BK];
  __shared__ __align__(16) s8 Bl[BN * BK];
  int n = *wlc; if (n > NB * TILES) n = NB * TILES;
  int tid = threadIdx.x, w = tid >> 6, lane = tid & 63;
  int wr = w >> 1, wc = w & 1;
  int lr = lane >> 3, ls = lane & 7, cs = ls ^ lr;
  int arow = wr * 64 + (lane & 31);
  int brow = wc * 64 + (lane & 31);
  int kg = lane >> 5;

  for (int wi = blockIdx.x; wi < n; wi += gridDim.x) {
    int e = wl[wi];
    int b = e >> 12, tile = e & 4095;
    int cut = thr[b] - MINT;
    int mt = tile >> 8, nt = tile & 255;
    int m0 = mt * BM, t0 = nt * BN;
    const s8* Ab = abf + (size_t)m0 * ASZ;
    const s8* Sb = sigsh + (size_t)b * 16 * SIGC;

    i32x16 acc[2][2];
    #pragma unroll
    for (int i = 0; i < 2; i++)
      #pragma unroll
      for (int j = 0; j < 2; j++)
        #pragma unroll
        for (int q = 0; q < 16; q++) acc[i][j][q] = 0;

    for (int k0 = 0; k0 < ASZ; k0 += BK) {
      #pragma unroll
      for (int i = 0; i < 8; i++) {
        int c = w * 8 + i;
        if (c < 16) {
          const s8* src = Ab + (size_t)(c * 8 + lr) * ASZ + k0 + cs * 16;
          __builtin_amdgcn_global_load_lds((const __attribute__((address_space(1))) void*)src,
              (__attribute__((address_space(3))) void*)(&Al[c * 1024]), 16, 0, 0);
        } else {
          int c2 = c - 16;
          int m = 8 * (c2 & 1) + lr;
          const s8* src = Sb + (size_t)m * SIGC + t0 + 16 * (c2 >> 1) + k0 + cs * 16;
          __builtin_amdgcn_global_load_lds((const __attribute__((address_space(1))) void*)src,
              (__attribute__((address_space(3))) void*)(&Bl[c2 * 1024]), 16, 0, 0);
        }
      }
      __syncthreads();
      #pragma unroll
      for (int kk = 0; kk < 4; kk++) {
        i32x4 af[2], bfr[2];
        #pragma unroll
        for (int mf = 0; mf < 2; mf++) {
          int row = arow + mf * 32;
          int slot = (kk * 2 + kg) ^ (row & 7);
          af[mf] = *(const i32x4*)&Al[row * BK + slot * 16];
        }
        #pragma unroll
        for (int nf = 0; nf < 2; nf++) {
          int row = brow + nf * 32;
          int slot = (kk * 2 + kg) ^ (row & 7);
          bfr[nf] = *(const i32x4*)&Bl[row * BK + slot * 16];
        }
        #pragma unroll
        for (int mf = 0; mf < 2; mf++)
          #pragma unroll
          for (int nf = 0; nf < 2; nf++)
            acc[mf][nf] = __builtin_amdgcn_mfma_i32_32x32x32_i8(af[mf], bfr[nf], acc[mf][nf], 0, 0, 0);
      }
      __syncthreads();
    }

    int rb = m0 + wr * 64 + 4 * kg;
    int cb = t0 + wc * 64 + (lane & 31);
    #pragma unroll
    for (int mf = 0; mf < 2; mf++)
      #pragma unroll
      for (int nf = 0; nf < 2; nf++)
        #pragma unroll
        for (int q = 0; q < 16; q++) {
          if (acc[mf][nf][q] >= cut) {
            int a = rb + mf * 32 + (q & 3) + 8 * (q >> 2);   // C/D 32x32: row=(q&3)+8*(q>>2)+4*(lane>>5)
            int t = cb + nf * 32;                            //           col=lane&31
            int p = atomicAdd(&ccnt[b], 1);
            if (p < CAP) cidx[b * CAP + p] = (a << 15) | t;
          }
        }
  }
}

// ---------------- rescore candidates exactly in fp32 (grid-stride waves) ----------------
__global__ void rescore_k(const float* __restrict__ atoms, const float* __restrict__ sigf,
                          const int* __restrict__ ccnt, const int* __restrict__ cidx,
                          float* __restrict__ cval) {
  int nwv = gridDim.x * 4;
  int gw = blockIdx.x * 4 + (threadIdx.x >> 6);
  int lane = threadIdx.x & 63;
  for (int b = 0; b < NB; b++) {
    int cnt = ccnt[b]; if (cnt > CAP) cnt = CAP;
    for (int ci = gw; ci < cnt; ci += nwv) {
      int idx = cidx[b * CAP + ci];
      int a = idx >> 15, t = idx & (NS - 1);
      const float* ap = atoms + (size_t)a * ASZ;
      const float* sp = sigf + (size_t)b * SIGC + t;
      float sum = 0.f;
      #pragma unroll
      for (int j = 0; j < 16; j++) { int k = lane + 64 * j; sum += ap[k] * sp[k]; }
      #pragma unroll
      for (int off = 32; off; off >>= 1) sum += __shfl_xor(sum, off, 64);
      if (lane == 0) cval[b * CAP + ci] = sum;
    }
  }
}

// ---------------- select top-64 per batch by rank counting (value desc, tie: index asc) ----------------
__global__ void select_k(const int* __restrict__ ccnt, const float* __restrict__ cval,
                         const int* __restrict__ cidx, float* __restrict__ sval,
                         int* __restrict__ sidx) {
  int b = blockIdx.x, tid = threadIdx.x;
  int cnt = ccnt[b]; if (cnt > CAP) cnt = CAP;
  __shared__ float lv[2048];
  __shared__ int li[2048];
  for (int ii = 0; ii * 256 < cnt; ii++) {
    int i = ii * 256 + tid;
    float vi = 0.f; int idi = 0; bool act = i < cnt;
    if (act) { vi = cval[b * CAP + i]; idi = cidx[b * CAP + i]; }
    int rank = 0;
    for (int c0 = 0; c0 < cnt; c0 += 2048) {
      int mchunk = cnt - c0; if (mchunk > 2048) mchunk = 2048;
      __syncthreads();
      for (int j = tid; j < mchunk; j += 256) {
        lv[j] = cval[b * CAP + c0 + j];
        li[j] = cidx[b * CAP + c0 + j];
      }
      __syncthreads();
      if (act)
        for (int j = 0; j < mchunk; j++)
          rank += (lv[j] > vi) || (lv[j] == vi && li[j] < idi);
    }
    if (act && rank < 64) { sval[b * 64 + rank] = vi; sidx[b * 64 + rank] = idi; }
  }
}

// ---------------- deterministic reconstruction (one thread per output sample) ----------------
__global__ void recon_k(const float* __restrict__ atoms, const float* __restrict__ sval,
                        const int* __restrict__ sidx, float* __restrict__ out) {
  int gp = blockIdx.x * 256 + threadIdx.x;       // 0 .. NB*NS-1
  int b = gp >> 15, p = gp & (NS - 1);
  __shared__ float vv[64];
  __shared__ int ii[64];
  if (threadIdx.x < 64) {
    vv[threadIdx.x] = sval[b * 64 + threadIdx.x];
    ii[threadIdx.x] = sidx[b * 64 + threadIdx.x];
  }
  __syncthreads();
  float acc = 0.f;
  for (int s = 0; s < 64; s++) {
    int idx = ii[s];
    int a = idx >> 15, t = idx & (NS - 1);
    int off = p - t;
    if (off >= 0 && off < ASZ) acc += vv[s] * atoms[(size_t)a * ASZ + off];
  }
  out[gp] = acc;
}

extern "C" void kernel_launch(void* const* d_in, const int* in_sizes, int n_in,
                              void* d_out, int out_size, void* d_ws, size_t ws_size,
                              hipStream_t stream) {
  const float* orig  = (const float*)d_in[0];   // (4,1,32768) fp32
  const float* atoms = (const float*)d_in[1];   // (2048,1024) fp32
  float* out = (float*)d_out;                   // (4,1,32768) fp32
  char* ws = (char*)d_ws;

  // workspace layout (16B-aligned), total ~5.3 MB
  s8*    abf   = (s8*)   (ws + 0);          // 2,097,152 : atoms i8
  s8*    sigsh = (s8*)   (ws + 2097152);    // 2,230,272 : 16 shifted padded i8 signal copies
  float* sigf  = (float*)(ws + 4327424);    //   557,568 : padded signal fp32
  int*   tmax  = (int*)  (ws + 4884992);    //    65,536 : per-tile maxima (int)
  int*   thr   = (int*)  (ws + 4950528);    //       256 : per-batch threshold (int)
  int*   ccnt  = (int*)  (ws + 4950784);    //       256 : candidate counts
  float* cval  = (float*)(ws + 4951040);    //   131,072 : candidate exact fp32 values
  int*   cidx  = (int*)  (ws + 5082112);    //   131,072 : candidate flat indices
  float* sval  = (float*)(ws + 5213184);    //     1,024 : selected values
  int*   sidx  = (int*)  (ws + 5214208);    //     1,024 : selected indices
  int*   wl    = (int*)  (ws + 5215232);    //    65,536 : gated-tile worklist
  int*   wlc   = (int*)  (ws + 5280768);    //       256 : worklist count

  prep_atoms_k<<<NA, 256, 0, stream>>>(atoms, abf, wlc);
  prep_sig_k<<<dim3((SIGC + 255) / 256, NB * 16), 256, 0, stream>>>(orig, sigsh, sigf);
  screen1<<<NB * TILES, 256, 0, stream>>>(abf, sigsh, tmax);
  thresh_k<<<NB, 256, 0, stream>>>(tmax, thr, ccnt, wl, wlc);
  screen2<<<1024, 256, 0, stream>>>(abf, sigsh, thr, wl, wlc, ccnt, cidx);
  rescore_k<<<128, 256, 0, stream>>>(atoms, sigf, ccnt, cidx, cval);
  select_k<<<NB, 256, 0, stream>>>(ccnt, cval, cidx, sval, sidx);
  recon_k<<<out_size / 256, 256, 0, stream>>>(atoms, sval, sidx, out);
}

// Round 3
// 316.400 us; speedup vs baseline: 2.0937x; 1.1301x over previous
//
#include <hip/hip_runtime.h>

#define NS     32768
#define NA     2048
#define ASZ    1024
#define NB     4
#define SIGC   34848          /* padded shifted-copy length, mult of 16 */
#define BM     128
#define BN     128
#define BK     128
#define TILES  4096           /* (NA/BM)*(NS/BN) */
#define CAP    8192
#define MINT   5080           /* margin 2.0 in int units (2.0*127*20) */
#define SSCALE 20.0f

typedef signed char s8;
typedef __attribute__((ext_vector_type(4))) int i32x4;

__device__ __forceinline__ int imax(int a, int b) { return a > b ? a : b; }

// ---------------- prep: atoms -> i8 (x127), also zero worklist counter ----------------
__global__ void prep_atoms_k(const float* __restrict__ atoms, s8* __restrict__ abf,
                             int* __restrict__ wlc) {
  if (blockIdx.x == 0 && threadIdx.x == 0) *wlc = 0;
  int a = blockIdx.x;
  const float* srow = atoms + (size_t)a * ASZ;
  s8* drow = abf + (size_t)a * ASZ;
  for (int k = threadIdx.x; k < ASZ; k += 256) {
    float q = fminf(127.f, fmaxf(-127.f, srow[k] * 127.f));
    drow[k] = (s8)__float2int_rn(q);
  }
}

// ---------------- prep: 16 shifted zero-padded i8 signal copies + fp32 copy ----------------
// sig_logical[i] = orig[i-512] (zero outside). copy m holds sig_logical[i+m], m=0..15.
__global__ void prep_sig_k(const float* __restrict__ orig, s8* __restrict__ sigsh,
                           float* __restrict__ sigf) {
  int i = blockIdx.x * 256 + threadIdx.x;
  if (i >= SIGC) return;
  int b = blockIdx.y >> 4, m = blockIdx.y & 15;
  int j = i + m - 512;
  float f = (j >= 0 && j < NS) ? orig[(size_t)b * NS + j] : 0.0f;
  float q = fminf(127.f, fmaxf(-127.f, f * SSCALE));
  sigsh[(size_t)(b * 16 + m) * SIGC + i] = (s8)__float2int_rn(q);
  if (m == 0) sigf[(size_t)b * SIGC + i] = f;
}

// ---------------- shared tile core: stage + K-loop, 16x16x64 i8 MFMA, 4x4 frag tile ----------------
// Wave w (wr=w>>1, wc=w&1) computes the 64x64 sub-tile at (wr*64, wc*64) as 4x4 16x16 frags.
__device__ __forceinline__ void tile_core(const s8* __restrict__ Ab, const s8* __restrict__ Sb,
                                          int t0, s8* Al, s8* Bl, int w, int lane,
                                          i32x4 acc[4][4]) {
  int wr = w >> 1, wc = w & 1;
  int lr = lane >> 3, ls = lane & 7, cs = ls ^ lr;   // stage: row lr of chunk, stored slot ls
  int arow = wr * 64 + (lane & 15);
  int brow = wc * 64 + (lane & 15);
  int kgrp = lane >> 4;                              // 0..3

  #pragma unroll
  for (int i = 0; i < 4; i++)
    #pragma unroll
    for (int j = 0; j < 4; j++)
      acc[i][j] = (i32x4){0, 0, 0, 0};

  for (int k0 = 0; k0 < ASZ; k0 += BK) {
    #pragma unroll
    for (int i = 0; i < 8; i++) {
      int c = w * 8 + i;                 // 32 chunks: 0..15 A, 16..31 B^T; 8 rows x 128B each
      if (c < 16) {
        const s8* src = Ab + (size_t)(c * 8 + lr) * ASZ + k0 + cs * 16;
        __builtin_amdgcn_global_load_lds((const __attribute__((address_space(1))) void*)src,
            (__attribute__((address_space(3))) void*)(&Al[c * 1024]), 16, 0, 0);
      } else {
        int c2 = c - 16;
        int m = 8 * (c2 & 1) + lr;       // shift-copy index = (c2*8+lr) & 15
        const s8* src = Sb + (size_t)m * SIGC + t0 + 16 * (c2 >> 1) + k0 + cs * 16;
        __builtin_amdgcn_global_load_lds((const __attribute__((address_space(1))) void*)src,
            (__attribute__((address_space(3))) void*)(&Bl[c2 * 1024]), 16, 0, 0);
      }
    }
    __syncthreads();
    #pragma unroll
    for (int kk = 0; kk < 2; kk++) {
      int sl = kk * 4 + kgrp;            // logical 16B K-slot 0..7
      i32x4 af[4], bfr[4];
      #pragma unroll
      for (int mf = 0; mf < 4; mf++) {
        int row = arow + mf * 16;
        af[mf] = *(const i32x4*)&Al[row * BK + ((sl ^ (row & 7)) * 16)];
      }
      #pragma unroll
      for (int nf = 0; nf < 4; nf++) {
        int row = brow + nf * 16;
        bfr[nf] = *(const i32x4*)&Bl[row * BK + ((sl ^ (row & 7)) * 16)];
      }
      #pragma unroll
      for (int mf = 0; mf < 4; mf++)
        #pragma unroll
        for (int nf = 0; nf < 4; nf++)
          acc[mf][nf] = __builtin_amdgcn_mfma_i32_16x16x64_i8(af[mf], bfr[nf], acc[mf][nf], 0, 0, 0);
    }
    __syncthreads();
  }
}

// ---------------- pass 1: i8 screening GEMM, per-tile max (exact int32) ----------------
__global__ __launch_bounds__(256, 4)
void screen1(const s8* __restrict__ abf, const s8* __restrict__ sigsh,
             int* __restrict__ tmax)
{
  __shared__ __align__(16) s8 Al[BM * BK];   // 16 KB
  __shared__ __align__(16) s8 Bl[BN * BK];   // 16 KB
  int bid0 = blockIdx.x;
  int bid  = (bid0 & 7) * ((NB * TILES) >> 3) + (bid0 >> 3);   // XCD swizzle (16384 % 8 == 0)
  int b = bid >> 12, tile = bid & 4095;
  int mt = tile >> 8, nt = tile & 255;
  int m0 = mt * BM, t0 = nt * BN;
  int tid = threadIdx.x, w = tid >> 6, lane = tid & 63;

  i32x4 acc[4][4];
  tile_core(abf + (size_t)m0 * ASZ, sigsh + (size_t)b * 16 * SIGC, t0, Al, Bl, w, lane, acc);

  int lmax = -2147483647;
  #pragma unroll
  for (int mf = 0; mf < 4; mf++)
    #pragma unroll
    for (int nf = 0; nf < 4; nf++)
      #pragma unroll
      for (int q = 0; q < 4; q++) lmax = imax(lmax, acc[mf][nf][q]);
  #pragma unroll
  for (int off = 32; off; off >>= 1) lmax = imax(lmax, __shfl_xor(lmax, off, 64));
  int* wredp = (int*)Al;
  if (lane == 0) wredp[w] = lmax;
  __syncthreads();
  if (tid == 0)
    tmax[b * TILES + tile] = imax(imax(wredp[0], wredp[1]), imax(wredp[2], wredp[3]));
}

// ---------------- threshold: 64th-largest tile-max (2-level histogram) + worklist ----------------
__global__ void thresh_k(const int* __restrict__ tmax, int* __restrict__ thr,
                         int* __restrict__ ccnt, int* __restrict__ wl, int* __restrict__ wlc) {
  int b = blockIdx.x, tid = threadIdx.x;
  __shared__ int hist[4096];
  __shared__ int tsum[256];
  __shared__ int hist2[256];
  __shared__ int sB1, sAbove, sThr;
  for (int i = tid; i < 4096; i += 256) hist[i] = 0;
  __syncthreads();
  for (int i = tid; i < TILES; i += 256) {
    unsigned u = (unsigned)tmax[b * TILES + i] ^ 0x80000000u;
    atomicAdd(&hist[u >> 20], 1);
  }
  __syncthreads();
  { int s = 0;
    for (int j = 0; j < 16; j++) s += hist[tid * 16 + j];
    tsum[tid] = s; }
  __syncthreads();
  if (tid == 0) {
    int cum = 0, T = 0;
    for (int t2 = 255; t2 >= 0; t2--) {
      if (cum + tsum[t2] >= 64) { T = t2; break; }
      cum += tsum[t2];
    }
    int B1 = T * 16;
    for (int bk = T * 16 + 15; bk >= T * 16; bk--) {
      if (cum + hist[bk] >= 64) { B1 = bk; break; }
      cum += hist[bk];
    }
    sB1 = B1; sAbove = cum;
  }
  __syncthreads();
  if (tid < 256) hist2[tid] = 0;
  __syncthreads();
  int B1 = sB1;
  for (int i = tid; i < TILES; i += 256) {
    unsigned u = (unsigned)tmax[b * TILES + i] ^ 0x80000000u;
    if ((int)(u >> 20) == B1) atomicAdd(&hist2[(u >> 12) & 255], 1);
  }
  __syncthreads();
  if (tid == 0) {
    int cum = sAbove, B2 = 0;
    for (int z = 255; z >= 0; z--) { cum += hist2[z]; if (cum >= 64) { B2 = z; break; } }
    unsigned ulow = ((unsigned)B1 << 20) | ((unsigned)B2 << 12);
    int t = (int)(ulow ^ 0x80000000u);
    sThr = t; thr[b] = t; ccnt[b] = 0;
  }
  __syncthreads();
  int cut = sThr - MINT;
  for (int i = tid; i < TILES; i += 256)
    if (tmax[b * TILES + i] >= cut) { int p = atomicAdd(wlc, 1); wl[p] = (b << 12) | i; }
}

// ---------------- pass 2: recompute gated tiles from worklist, emit candidate indices ----------------
__global__ __launch_bounds__(256, 4)
void screen2(const s8* __restrict__ abf, const s8* __restrict__ sigsh,
             const int* __restrict__ thr, const int* __restrict__ wl,
             const int* __restrict__ wlc, int* __restrict__ ccnt, int* __restrict__ cidx)
{
  __shared__ __align__(16) s8 Al[BM * BK];
  __shared__ __align__(16) s8 Bl[BN * BK];
  int n = *wlc; if (n > NB * TILES) n = NB * TILES;
  int tid = threadIdx.x, w = tid >> 6, lane = tid & 63;
  int wr = w >> 1, wc = w & 1;
  int kgrp = lane >> 4;

  for (int wi = blockIdx.x; wi < n; wi += gridDim.x) {
    int e = wl[wi];
    int b = e >> 12, tile = e & 4095;
    int cut = thr[b] - MINT;
    int mt = tile >> 8, nt = tile & 255;
    int m0 = mt * BM, t0 = nt * BN;

    i32x4 acc[4][4];
    tile_core(abf + (size_t)m0 * ASZ, sigsh + (size_t)b * 16 * SIGC, t0, Al, Bl, w, lane, acc);

    int rb = m0 + wr * 64 + 4 * kgrp;
    int cb = t0 + wc * 64 + (lane & 15);
    #pragma unroll
    for (int mf = 0; mf < 4; mf++)
      #pragma unroll
      for (int nf = 0; nf < 4; nf++)
        #pragma unroll
        for (int q = 0; q < 4; q++) {
          if (acc[mf][nf][q] >= cut) {
            int a = rb + mf * 16 + q;        // C/D 16x16: row=(lane>>4)*4+reg
            int t = cb + nf * 16;            //           col=lane&15
            int p = atomicAdd(&ccnt[b], 1);
            if (p < CAP) cidx[b * CAP + p] = (a << 15) | t;
          }
        }
  }
}

// ---------------- rescore candidates exactly in fp32 (grid-stride waves) ----------------
__global__ void rescore_k(const float* __restrict__ atoms, const float* __restrict__ sigf,
                          const int* __restrict__ ccnt, const int* __restrict__ cidx,
                          float* __restrict__ cval) {
  int nwv = gridDim.x * 4;
  int gw = blockIdx.x * 4 + (threadIdx.x >> 6);
  int lane = threadIdx.x & 63;
  for (int b = 0; b < NB; b++) {
    int cnt = ccnt[b]; if (cnt > CAP) cnt = CAP;
    for (int ci = gw; ci < cnt; ci += nwv) {
      int idx = cidx[b * CAP + ci];
      int a = idx >> 15, t = idx & (NS - 1);
      const float* ap = atoms + (size_t)a * ASZ;
      const float* sp = sigf + (size_t)b * SIGC + t;
      float sum = 0.f;
      #pragma unroll
      for (int j = 0; j < 16; j++) { int k = lane + 64 * j; sum += ap[k] * sp[k]; }
      #pragma unroll
      for (int off = 32; off; off >>= 1) sum += __shfl_xor(sum, off, 64);
      if (lane == 0) cval[b * CAP + ci] = sum;
    }
  }
}

// ---------------- select top-64 per batch by rank counting (value desc, tie: index asc) ----------------
__global__ void select_k(const int* __restrict__ ccnt, const float* __restrict__ cval,
                         const int* __restrict__ cidx, float* __restrict__ sval,
                         int* __restrict__ sidx) {
  int b = blockIdx.x, tid = threadIdx.x;
  int cnt = ccnt[b]; if (cnt > CAP) cnt = CAP;
  __shared__ float lv[2048];
  __shared__ int li[2048];
  for (int ii = 0; ii * 256 < cnt; ii++) {
    int i = ii * 256 + tid;
    float vi = 0.f; int idi = 0; bool act = i < cnt;
    if (act) { vi = cval[b * CAP + i]; idi = cidx[b * CAP + i]; }
    int rank = 0;
    for (int c0 = 0; c0 < cnt; c0 += 2048) {
      int mchunk = cnt - c0; if (mchunk > 2048) mchunk = 2048;
      __syncthreads();
      for (int j = tid; j < mchunk; j += 256) {
        lv[j] = cval[b * CAP + c0 + j];
        li[j] = cidx[b * CAP + c0 + j];
      }
      __syncthreads();
      if (act)
        for (int j = 0; j < mchunk; j++)
          rank += (lv[j] > vi) || (lv[j] == vi && li[j] < idi);
    }
    if (act && rank < 64) { sval[b * 64 + rank] = vi; sidx[b * 64 + rank] = idi; }
  }
}

// ---------------- deterministic reconstruction (one thread per output sample) ----------------
__global__ void recon_k(const float* __restrict__ atoms, const float* __restrict__ sval,
                        const int* __restrict__ sidx, float* __restrict__ out) {
  int gp = blockIdx.x * 256 + threadIdx.x;       // 0 .. NB*NS-1
  int b = gp >> 15, p = gp & (NS - 1);
  __shared__ float vv[64];
  __shared__ int ii[64];
  if (threadIdx.x < 64) {
    vv[threadIdx.x] = sval[b * 64 + threadIdx.x];
    ii[threadIdx.x] = sidx[b * 64 + threadIdx.x];
  }
  __syncthreads();
  float acc = 0.f;
  for (int s = 0; s < 64; s++) {
    int idx = ii[s];
    int a = idx >> 15, t = idx & (NS - 1);
    int off = p - t;
    if (off >= 0 && off < ASZ) acc += vv[s] * atoms[(size_t)a * ASZ + off];
  }
  out[gp] = acc;
}

extern "C" void kernel_launch(void* const* d_in, const int* in_sizes, int n_in,
                              void* d_out, int out_size, void* d_ws, size_t ws_size,
                              hipStream_t stream) {
  const float* orig  = (const float*)d_in[0];   // (4,1,32768) fp32
  const float* atoms = (const float*)d_in[1];   // (2048,1024) fp32
  float* out = (float*)d_out;                   // (4,1,32768) fp32
  char* ws = (char*)d_ws;

  // workspace layout (16B-aligned), total ~5.3 MB
  s8*    abf   = (s8*)   (ws + 0);          // 2,097,152 : atoms i8
  s8*    sigsh = (s8*)   (ws + 2097152);    // 2,230,272 : 16 shifted padded i8 signal copies
  float* sigf  = (float*)(ws + 4327424);    //   557,568 : padded signal fp32
  int*   tmax  = (int*)  (ws + 4884992);    //    65,536 : per-tile maxima (int)
  int*   thr   = (int*)  (ws + 4950528);    //       256 : per-batch threshold (int)
  int*   ccnt  = (int*)  (ws + 4950784);    //       256 : candidate counts
  float* cval  = (float*)(ws + 4951040);    //   131,072 : candidate exact fp32 values
  int*   cidx  = (int*)  (ws + 5082112);    //   131,072 : candidate flat indices
  float* sval  = (float*)(ws + 5213184);    //     1,024 : selected values
  int*   sidx  = (int*)  (ws + 5214208);    //     1,024 : selected indices
  int*   wl    = (int*)  (ws + 5215232);    //    65,536 : gated-tile worklist
  int*   wlc   = (int*)  (ws + 5280768);    //       256 : worklist count

  prep_atoms_k<<<NA, 256, 0, stream>>>(atoms, abf, wlc);
  prep_sig_k<<<dim3((SIGC + 255) / 256, NB * 16), 256, 0, stream>>>(orig, sigsh, sigf);
  screen1<<<NB * TILES, 256, 0, stream>>>(abf, sigsh, tmax);
  thresh_k<<<NB, 256, 0, stream>>>(tmax, thr, ccnt, wl, wlc);
  screen2<<<1024, 256, 0, stream>>>(abf, sigsh, thr, wl, wlc, ccnt, cidx);
  rescore_k<<<128, 256, 0, stream>>>(atoms, sigf, ccnt, cidx, cval);
  select_k<<<NB, 256, 0, stream>>>(ccnt, cval, cidx, sval, sidx);
  recon_k<<<out_size / 256, 256, 0, stream>>>(atoms, sval, sidx, out);
}